// Round 8
// baseline (46.958 us; speedup 1.0000x reference)
//
#include <hip/hip_runtime.h>
#include <hip/hip_bf16.h>

// AlignmentLoss: loss = -(sum(tril(G,-1)*eq) / (sum(tril(eq,-1)) * ||tril(G,-1)||_F))
// with G = A A^T, A: 4096x1024 fp32, target: 4096 int32 (classes < 1000).
//
//   S1 = 0.5*(sum_c ||s_c||^2 - sum_i ||a_i||^2)   (exact fp32/fp64 path)
//   S2 = 0.5*(sum_c n_c^2 - N)
//   S3 = sum_{i>j} g_ij^2  -- lower-triangle 128x128 tiles of G = A A^T in
//        bf16 MFMA, K=1024 along A's natural layout, fused masked Frobenius.
//   loss = -S1 / (S2 * sqrt(S3))
//
// R8 change (isolated vs R7): kfrob wave decomposition 8x(64x32) -> 4x(64x64)
// (4x4 MFMA acc per wave, 256 threads).  Fragment LDS traffic per block-K-step
// drops 48KB -> 32KB (21.8 -> 32.8 FLOP/B); the LDS read pipe was measured as
// the wall (~1000 cy/K-step-pair ~ 96 b128 reads; MFMA needs only ~620).
// Pipeline (dbuf + counted vmcnt(4)), bank swizzle, XCD swizzle retained.

typedef __attribute__((ext_vector_type(8))) short short8;
typedef __attribute__((ext_vector_type(4))) float f32x4;

#define N_ROWS 4096
#define D_DIM  1024
#define N_CLS  1000
#define NTILE  32          // 4096 / 128 block-rows
#define NBLK   528         // NTILE*(NTILE+1)/2 lower-triangle tiles
#define NK     32          // 1024 / BK,  BK = 32

__device__ __forceinline__ unsigned short f2bf(float f) {
  unsigned u = __float_as_uint(f);
  u += 0x7fffu + ((u >> 16) & 1u);   // round-to-nearest-even
  return (unsigned short)(u >> 16);
}

__device__ __forceinline__ void gload16(const short* g, const char* l) {
  __builtin_amdgcn_global_load_lds(
      (const __attribute__((address_space(1))) unsigned*)g,
      (__attribute__((address_space(3))) unsigned*)(void*)l, 16, 0, 0);
}

// ---------------------------------------------------------------------------
// kprep: blocks 0..511  = convert A->bf16 + row-norm partials
//        blocks 512..   = per-class sum-vector norm + count
// ---------------------------------------------------------------------------
__global__ void __launch_bounds__(256) kprep(const float* __restrict__ A,
                                             const int* __restrict__ target,
                                             short* __restrict__ Ab,
                                             double* __restrict__ rowp,
                                             double* __restrict__ cssp,
                                             int* __restrict__ cntp) {
  const int tid = threadIdx.x, lane = tid & 63, w = tid >> 6;

  if (blockIdx.x < 512) {
    __shared__ double wr2[4];
    const int row0 = blockIdx.x * 8;
    double ls = 0.0;
#pragma unroll
    for (int rr = 0; rr < 2; ++rr) {
      const int i = row0 + w * 2 + rr;
      const float4* src = (const float4*)(A + (size_t)i * D_DIM);
      short4* dst = (short4*)(Ab + (size_t)i * D_DIM);
      float s = 0.f;
#pragma unroll
      for (int c = 0; c < 4; ++c) {
        const float4 v = src[lane + c * 64];
        s += v.x * v.x + v.y * v.y + v.z * v.z + v.w * v.w;
        short4 o;
        o.x = (short)f2bf(v.x); o.y = (short)f2bf(v.y);
        o.z = (short)f2bf(v.z); o.w = (short)f2bf(v.w);
        dst[lane + c * 64] = o;
      }
#pragma unroll
      for (int off = 32; off; off >>= 1) s += __shfl_down(s, off);
      if (lane == 0) ls += (double)s;
    }
    if (lane == 0) wr2[w] = ls;
    __syncthreads();
    if (tid == 0) rowp[blockIdx.x] = wr2[0] + wr2[1] + wr2[2] + wr2[3];
  } else {
    __shared__ int list[N_ROWS];
    __shared__ int lcnt;
    __shared__ float wred[4];
    const int c = blockIdx.x - 512;
    if (c >= N_CLS) return;
    if (tid == 0) lcnt = 0;
    __syncthreads();
    for (int j = tid; j < N_ROWS; j += 256)
      if (target[j] == c) { int p = atomicAdd(&lcnt, 1); list[p] = j; }
    __syncthreads();
    const int n = lcnt;
    float4 acc = make_float4(0.f, 0.f, 0.f, 0.f);
    for (int m = 0; m < n; ++m) {
      const float4 v = *(const float4*)(A + (size_t)list[m] * D_DIM + tid * 4);
      acc.x += v.x; acc.y += v.y; acc.z += v.z; acc.w += v.w;
    }
    float s = acc.x * acc.x + acc.y * acc.y + acc.z * acc.z + acc.w * acc.w;
#pragma unroll
    for (int off = 32; off; off >>= 1) s += __shfl_down(s, off);
    if (lane == 0) wred[w] = s;
    __syncthreads();
    if (tid == 0) {
      cssp[c] = (double)(wred[0] + wred[1] + wred[2] + wred[3]);
      cntp[c] = n;
    }
  }
}

// ---------------------------------------------------------------------------
// kfrob: lower-triangle 128x128 tiles of G = Ab*Ab^T, bf16 MFMA, 4 waves
// (2x2, 64x64 per wave, 4x4 acc), dbuf + counted-vmcnt pipeline, bank-
// swizzled LDS, fused masked Frobenius.  Grid NBLK=528 x 256 threads.
// ---------------------------------------------------------------------------
__global__ void __launch_bounds__(256, 2) kfrob(const short* __restrict__ Ab,
                                                double* __restrict__ frobp) {
  __shared__ __align__(16) short As[2][128 * 32];   // 2 x 8 KB
  __shared__ __align__(16) short Bs[2][128 * 32];   // 2 x 8 KB
  __shared__ double wred[4];
  const int tid = threadIdx.x, lane = tid & 63, w = tid >> 6;

  // XCD-aware swizzle: 528 = 8 * 66; XCD x gets contiguous triangle chunk.
  const int b = (blockIdx.x & 7) * 66 + (blockIdx.x >> 3);

  // decode lower-triangle pair: b = bi*(bi+1)/2 + bj, bj <= bi
  int bi = (int)((sqrtf(8.f * (float)b + 1.f) - 1.f) * 0.5f);
  while ((bi + 1) * (bi + 2) / 2 <= b) ++bi;
  while (bi * (bi + 1) / 2 > b) --bi;
  const int bj = b - bi * (bi + 1) / 2;
  const bool diag = (bi == bj);

  const short* Pa = Ab + (size_t)(bi * 128) * D_DIM;
  const short* Pb = Ab + (size_t)(bj * 128) * D_DIM;

  f32x4 acc[4][4];
#pragma unroll
  for (int m = 0; m < 4; ++m)
#pragma unroll
    for (int n = 0; n < 4; ++n) acc[m][n] = (f32x4){0.f, 0.f, 0.f, 0.f};

  const int wr = w >> 1, wc = w & 1;             // wave tile: rows 64*wr, cols 64*wc
  const int row16 = lane & 15, ck = lane >> 4;   // ck = 16-B chunk index 0..3

  // staging: 256 thr x 16B x 2 issues = one [128][32]-short buffer (A and B).
  // Source chunk pre-swizzled (chunk ^= (row>>1)&3); LDS linear.
  // issue s covers rows s*64 + (tid>>2); note ((s*64+r)>>1)&3 == ((r)>>1)&3.
  const int sr = tid >> 2;
  const int scS = (tid & 3) ^ ((sr >> 1) & 3);
  const size_t g0 = (size_t)sr * D_DIM + scS * 8;          // rows 0..63
  const size_t g1 = (size_t)(sr + 64) * D_DIM + scS * 8;   // rows 64..127
  const int l0 = w * 1024;                                 // = tid*16 - lane*16
  const int l1 = 4096 + w * 1024;

#define STAGE(buf, k0)                                                      \
  do {                                                                      \
    gload16(Pa + g0 + (k0), (const char*)As[buf] + l0);                     \
    gload16(Pa + g1 + (k0), (const char*)As[buf] + l1);                     \
    gload16(Pb + g0 + (k0), (const char*)Bs[buf] + l0);                     \
    gload16(Pb + g1 + (k0), (const char*)Bs[buf] + l1);                     \
  } while (0)

  // swizzled ds_read offset (in shorts) for row R, chunk ck
#define SWZ(R) (((R) * 32) + ((ck ^ (((R) >> 1) & 3)) * 8))

#define COMPUTE(buf)                                                        \
  do {                                                                      \
    short8 af[4], bf[4];                                                    \
    _Pragma("unroll")                                                       \
    for (int m = 0; m < 4; ++m)                                             \
      af[m] = *(const short8*)&As[buf][SWZ(wr * 64 + m * 16 + row16)];      \
    _Pragma("unroll")                                                       \
    for (int n = 0; n < 4; ++n)                                             \
      bf[n] = *(const short8*)&Bs[buf][SWZ(wc * 64 + n * 16 + row16)];      \
    _Pragma("unroll")                                                       \
    for (int m = 0; m < 4; ++m)                                             \
      _Pragma("unroll")                                                     \
      for (int n = 0; n < 4; ++n)                                           \
        acc[m][n] = __builtin_amdgcn_mfma_f32_16x16x32_bf16(af[m], bf[n],   \
                                                            acc[m][n], 0, 0, 0);\
  } while (0)

  STAGE(0, 0);                       // prologue: tile 0 in flight (4 loads)
  int cur = 0;
#pragma unroll 1
  for (int t = 0; t < NK - 1; ++t) {
    STAGE(cur ^ 1, (t + 1) * 32);    // issue next tile (4 loads/thread)
    asm volatile("s_waitcnt vmcnt(4)" ::: "memory");   // wait tile t only
    __builtin_amdgcn_sched_barrier(0);
    __builtin_amdgcn_s_barrier();    // all waves: tile t resident
    __builtin_amdgcn_sched_barrier(0);
    COMPUTE(cur);
    asm volatile("s_waitcnt lgkmcnt(0)" ::: "memory"); // all ds_reads retired
    __builtin_amdgcn_sched_barrier(0);
    __builtin_amdgcn_s_barrier();    // safe to overwrite buf cur next iter
    __builtin_amdgcn_sched_barrier(0);
    cur ^= 1;
  }
  asm volatile("s_waitcnt vmcnt(0)" ::: "memory");     // last tile resident
  __builtin_amdgcn_sched_barrier(0);
  __builtin_amdgcn_s_barrier();
  __builtin_amdgcn_sched_barrier(0);
  COMPUTE(cur);
#undef STAGE
#undef COMPUTE
#undef SWZ

  float fs = 0.f;
  if (!diag) {
#pragma unroll
    for (int m = 0; m < 4; ++m)
#pragma unroll
      for (int n = 0; n < 4; ++n)
#pragma unroll
        for (int q = 0; q < 4; ++q) fs += acc[m][n][q] * acc[m][n][q];
  } else {
    const int rbase = (lane >> 4) * 4, cbase = lane & 15;
#pragma unroll
    for (int m = 0; m < 4; ++m)
#pragma unroll
      for (int n = 0; n < 4; ++n)
#pragma unroll
        for (int q = 0; q < 4; ++q) {
          const int rl = wr * 64 + m * 16 + rbase + q;
          const int cl = wc * 64 + n * 16 + cbase;
          if (rl > cl) fs += acc[m][n][q] * acc[m][n][q];
        }
  }
#pragma unroll
  for (int off = 32; off; off >>= 1) fs += __shfl_down(fs, off);
  if (lane == 0) wred[w] = (double)fs;
  __syncthreads();
  if (tid == 0)
    frobp[b] = wred[0] + wred[1] + wred[2] + wred[3];
}

// ---------------------------------------------------------------------------
// kfinal: fp64 reduce + scalar math.
// ---------------------------------------------------------------------------
__global__ void __launch_bounds__(256) kfinal(const double* __restrict__ rowp,
                                              const double* __restrict__ cssp,
                                              const int* __restrict__ cntp,
                                              const double* __restrict__ frobp,
                                              float* __restrict__ out) {
  __shared__ double red[256];
  const int tid = threadIdx.x;
  double lsum = rowp[tid] + rowp[tid + 256];
  double lcss = 0.0, lcnn = 0.0, lfr = 0.0;
  for (int c = tid; c < N_CLS; c += 256) {
    lcss += cssp[c];
    const double nc = (double)cntp[c];
    lcnn += nc * nc;
  }
  for (int c = tid; c < NBLK; c += 256) lfr += frobp[c];

  double vals[4] = {lsum, lcss, lcnn, lfr};
  double res[4];
  for (int v = 0; v < 4; ++v) {
    red[tid] = vals[v];
    __syncthreads();
    for (int s = 128; s; s >>= 1) {
      if (tid < s) red[tid] += red[tid + s];
      __syncthreads();
    }
    res[v] = red[0];
    __syncthreads();
  }
  if (tid == 0) {
    const double sumr = res[0], css = res[1], cnn = res[2], frob = res[3];
    const double S1 = 0.5 * (css - sumr);
    const double S2 = 0.5 * (cnn - (double)N_ROWS);
    const double S3 = frob;
    out[0] = (float)(-(S1 / (S2 * sqrt(S3))));
  }
}

extern "C" void kernel_launch(void* const* d_in, const int* in_sizes, int n_in,
                              void* d_out, int out_size, void* d_ws, size_t ws_size,
                              hipStream_t stream) {
  const float* A = (const float*)d_in[0];
  const int* target = (const int*)d_in[1];
  float* out = (float*)d_out;

  char* ws = (char*)d_ws;
  short*  Ab    = (short*)ws;                                   // 8,388,608 B
  double* rowp  = (double*)(ws + 8388608);                      // 512 doubles
  double* cssp  = (double*)(ws + 8388608 + 4096);               // 1000 doubles
  int*    cntp  = (int*)   (ws + 8388608 + 4096 + 8000);        // 1000 ints (pad 4096)
  double* frobp = (double*)(ws + 8388608 + 4096 + 8000 + 4096); // 528 doubles

  kprep<<<512 + N_CLS, 256, 0, stream>>>(A, target, Ab, rowp, cssp, cntp);
  kfrob<<<NBLK, 256, 0, stream>>>(Ab, frobp);
  kfinal<<<1, 256, 0, stream>>>(rowp, cssp, cntp, frobp, out);
}